// Round 1
// 787.217 us; speedup vs baseline: 1.1349x; 1.1349x over previous
//
#include <hip/hip_runtime.h>
#include <hip/hip_bf16.h>
#include <math.h>

typedef __attribute__((ext_vector_type(8))) short short8;
typedef __attribute__((ext_vector_type(4))) float f32x4;

__device__ __forceinline__ float bf2f(__hip_bfloat16 h) { return __bfloat162float(h); }
__device__ __forceinline__ __hip_bfloat16 f2bf(float f) { return __float2bfloat16(f); }

// tanh-approx GELU (max dev from exact ~3e-4; threshold is 0.15)
__device__ __forceinline__ float gelu_f(float v) {
  const float u = v * (0.7978845608f + 0.0356774081f * v * v);
  const float e = __expf(2.0f * u);                                // e^{2u}
  const float t = 1.0f - 2.0f * __builtin_amdgcn_rcpf(e + 1.0f);   // tanh(u)
  return 0.5f * v * (1.0f + t);
}

// ---------------- LayerNorm over 768, fp32 in -> bf16 out ----------------
__global__ __launch_bounds__(256) void ln_kernel(
    const float* __restrict__ in, const float* __restrict__ g,
    const float* __restrict__ b, __hip_bfloat16* __restrict__ out)
{
  __shared__ float sm1[4], sm2[4];
  const int row = blockIdx.x;
  const int tid = threadIdx.x;
  const float* p = in + (size_t)row * 768;
  float x0 = p[tid], x1 = p[tid + 256], x2 = p[tid + 512];
  float s = x0 + x1 + x2;
  #pragma unroll
  for (int off = 32; off > 0; off >>= 1) s += __shfl_down(s, off, 64);
  const int l = tid & 63, w = tid >> 6;
  if (l == 0) sm1[w] = s;
  __syncthreads();
  const float mu = (sm1[0] + sm1[1] + sm1[2] + sm1[3]) * (1.0f / 768.0f);
  const float d0 = x0 - mu, d1 = x1 - mu, d2 = x2 - mu;
  float ss = d0*d0 + d1*d1 + d2*d2;
  #pragma unroll
  for (int off = 32; off > 0; off >>= 1) ss += __shfl_down(ss, off, 64);
  if (l == 0) sm2[w] = ss;
  __syncthreads();
  const float var = (sm2[0] + sm2[1] + sm2[2] + sm2[3]) * (1.0f / 768.0f);
  const float rstd = rsqrtf(var + 1e-6f);
  __hip_bfloat16* q = out + (size_t)row * 768;
  q[tid]       = f2bf(d0 * rstd * g[tid]       + b[tid]);
  q[tid + 256] = f2bf(d1 * rstd * g[tid + 256] + b[tid + 256]);
  q[tid + 512] = f2bf(d2 * rstd * g[tid + 512] + b[tid + 512]);
}

// ---------------- criss-cross attention core, 2 kf per thread ----------------
__global__ __launch_bounds__(256) void attn_kernel(
    const __hip_bfloat162* __restrict__ qkv, __hip_bfloat162* __restrict__ ctx)
{
  const long t = (long)blockIdx.x * 256 + threadIdx.x;  // one per (row, kf-pair)
  const long row = t >> 7;
  const int kp = (int)(t & 127);                        // pair index 0..127
  const __hip_bfloat162* p = qkv + row * 1152;          // 2304 bf16 = 1152 pairs
  float q[3][2], k[3][2], v[3][2];
  #pragma unroll
  for (int c = 0; c < 3; ++c) {
    __hip_bfloat162 qq = p[c*384 + kp];
    __hip_bfloat162 kk = p[c*384 + 128 + kp];
    __hip_bfloat162 vv = p[c*384 + 256 + kp];
    q[c][0] = __low2float(qq); q[c][1] = __high2float(qq);
    k[c][0] = __low2float(kk); k[c][1] = __high2float(kk);
    v[c][0] = __low2float(vv); v[c][1] = __high2float(vv);
  }
  float o[3][2] = {};
  #pragma unroll
  for (int u = 0; u < 2; ++u) {
    #pragma unroll
    for (int c = 0; c < 3; ++c) {
      const float s0 = q[c][u]*k[0][u]*0.0625f, s1 = q[c][u]*k[1][u]*0.0625f, s2 = q[c][u]*k[2][u]*0.0625f;
      const float m = fmaxf(s0, fmaxf(s1, s2));
      const float e0 = __expf(s0-m), e1 = __expf(s1-m), e2 = __expf(s2-m);
      const float inv = v[c][u] / (e0 + e1 + e2);
      o[0][u] += e0*inv; o[1][u] += e1*inv; o[2][u] += e2*inv;
    }
  }
  __hip_bfloat162* po = ctx + row * 384;
  #pragma unroll
  for (int d = 0; d < 3; ++d)
    po[d*128 + kp] = __hip_bfloat162{f2bf(o[d][0]), f2bf(o[d][1])};
}

// ---------------- LDS-tiled fp32 [K,N] -> bf16 [N,K] transpose ----------------
__global__ __launch_bounds__(256) void transpose_bf16_kernel(
    const float* __restrict__ in, __hip_bfloat16* __restrict__ out, int K, int N)
{
  __shared__ float tile[32][33];
  in  += (size_t)blockIdx.z * K * N;
  out += (size_t)blockIdx.z * K * N;
  const int n0 = blockIdx.x * 32;
  const int k0 = blockIdx.y * 32;
  const int tx = threadIdx.x & 31, ty = threadIdx.x >> 5;   // 32 x 8
  #pragma unroll
  for (int r = 0; r < 32; r += 8)
    tile[ty + r][tx] = in[(size_t)(k0 + ty + r) * N + n0 + tx];
  __syncthreads();
  #pragma unroll
  for (int r = 0; r < 32; r += 8)
    out[(size_t)(n0 + ty + r) * K + k0 + tx] = f2bf(tile[tx][ty + r]);
}

// ---------------- bf16 MFMA GEMM, B^T input, BK=32, dbuf-pipelined ----------------
// (kept for fc_out, which is memory-bound at N=256/K=256)
#define BM 128
#define BN 128
#define BK 32

template<int MODE>
__global__ __launch_bounds__(256) void gemm_bt_kernel(
    const __hip_bfloat16* __restrict__ A, int lda, long strideA,
    const __hip_bfloat16* __restrict__ Bt, int ldb, long strideB,
    float* __restrict__ Cf, __hip_bfloat16* __restrict__ Cb, int ldc, long strideC,
    const float* __restrict__ bias, long strideBias,
    const float* __restrict__ res,
    int K)
{
  __shared__ __align__(16) char sAll[2 * 16384];   // 2 x (sA 8KB + sB 8KB)

  const int z = blockIdx.z;
  A    += (size_t)z * strideA;
  Bt   += (size_t)z * strideB;
  bias += (size_t)z * strideBias;
  const long cOff = (long)z * strideC;

  const long tileM = (long)blockIdx.x * BM;   // M fastest
  const int  tileN = blockIdx.y * BN;

  const int tid  = threadIdx.x;
  const int lane = tid & 63;
  const int wv   = tid >> 6;
  const int waveM = (wv & 1) * 64;
  const int waveN = (wv >> 1) * 64;

  const int srow  = tid >> 2;                          // 0..63
  const int selem = ((tid & 3) ^ ((srow >> 1) & 3)) * 8;
  const int frow = lane & 15;
  const int fkb  = (((lane >> 4) ^ ((frow >> 1) & 3)) << 4);  // swizzled byte offs

  const __hip_bfloat16* Ab = A  + tileM * (size_t)lda + selem;
  const __hip_bfloat16* Bb = Bt + (long)tileN * (size_t)ldb + selem;

  f32x4 acc[4][4] = {};

  const int T = K / BK;

  {
    #pragma unroll
    for (int hh = 0; hh < 2; ++hh) {
      const int r = hh * 64 + srow;
      __builtin_amdgcn_global_load_lds(
          (const __attribute__((address_space(1))) void*)(Ab + (size_t)r * lda),
          (__attribute__((address_space(3))) void*)(sAll + hh*4096 + tid*16), 16, 0, 0);
      __builtin_amdgcn_global_load_lds(
          (const __attribute__((address_space(1))) void*)(Bb + (size_t)r * ldb),
          (__attribute__((address_space(3))) void*)(sAll + 8192 + hh*4096 + tid*16), 16, 0, 0);
    }
  }

  for (int t = 0; t < T; ++t) {
    const int buf = (t & 1) * 16384;
    if (t + 1 < T) {
      const int nbuf = 16384 - buf;
      const int k0 = (t + 1) * BK;
      #pragma unroll
      for (int hh = 0; hh < 2; ++hh) {
        const int r = hh * 64 + srow;
        __builtin_amdgcn_global_load_lds(
            (const __attribute__((address_space(1))) void*)(Ab + (size_t)r * lda + k0),
            (__attribute__((address_space(3))) void*)(sAll + nbuf + hh*4096 + tid*16), 16, 0, 0);
        __builtin_amdgcn_global_load_lds(
            (const __attribute__((address_space(1))) void*)(Bb + (size_t)r * ldb + k0),
            (__attribute__((address_space(3))) void*)(sAll + nbuf + 8192 + hh*4096 + tid*16), 16, 0, 0);
      }
      asm volatile("s_waitcnt vmcnt(4)" ::: "memory");   // drain tile t only
    } else {
      asm volatile("s_waitcnt vmcnt(0)" ::: "memory");
    }
    __builtin_amdgcn_s_barrier();                        // buf[t] published

    const char* sAb = sAll + buf;
    const char* sBb = sAb + 8192;
    short8 aF[4], bF[4];
    #pragma unroll
    for (int i = 0; i < 4; ++i)
      aF[i] = *(const short8*)(sAb + (waveM + i*16 + frow) * 64 + fkb);
    #pragma unroll
    for (int j = 0; j < 4; ++j)
      bF[j] = *(const short8*)(sBb + (waveN + j*16 + frow) * 64 + fkb);
    #pragma unroll
    for (int i = 0; i < 4; ++i)
      #pragma unroll
      for (int j = 0; j < 4; ++j)
        acc[i][j] = __builtin_amdgcn_mfma_f32_16x16x32_bf16(aF[i], bF[j], acc[i][j], 0, 0, 0);

    __builtin_amdgcn_s_barrier();                        // readers of buf[t] done
  }

  #pragma unroll
  for (int i = 0; i < 4; ++i) {
    const long row0 = tileM + waveM + i*16 + ((lane >> 4) * 4);
    #pragma unroll
    for (int j = 0; j < 4; ++j) {
      const int col = tileN + waveN + j*16 + (lane & 15);
      const float bv = bias[col];
      #pragma unroll
      for (int r = 0; r < 4; ++r) {
        const long idx = cOff + (row0 + r) * (long)ldc + col;
        const float v = acc[i][j][r] + bv;
        if (MODE == 0) {
          Cb[idx] = f2bf(v);
        } else if (MODE == 1 || MODE == 3) {
          Cf[idx] = v + res[idx];
        } else {
          Cb[idx] = f2bf(gelu_f(v));
        }
      }
    }
  }
}

// ---------------- 256x256 8-wave multi-phase bf16 GEMM (BK=64) ----------------
// Structure per K-tile (4 phases), HK-style counted-vmcnt pipeline:
//   P1 (quad 0,0): vmcnt(4); barrier; stage A0(t+1); ds_read A0-frags(8)+B0-frags(4); 16 MFMA
//   P2 (quad 0,1): stage B0(t+1); vmcnt(6); barrier; ds_read B1-frags(4);   16 MFMA (reuse A)
//   P3 (quad 1,1): stage B1(t+1); vmcnt(6); barrier; ds_read A1-frags(8);   16 MFMA (reuse B1)
//   P4 (quad 1,0): stage A1(t+1);                                           16 MFMA (regs only)
// Stages always target the other (dead) buffer; vmcnt never drains to 0 in the
// main loop -> 3-4 half-tiles in flight across barriers.
// LDS layout per buffer (64 KB): A-half0 | A-half1 | B-half0 | B-half1 (16 KB each),
// rows of 128 B; chunk c (16 B) of row r stored at granule c ^ (r&7). Store side is
// pre-swizzled on the GLOBAL source address (global_load_lds dest stays linear);
// read side applies the same XOR -> conflict-free ds_read_b128.
#define GLL16(src, dst) __builtin_amdgcn_global_load_lds( \
    (const __attribute__((address_space(1))) void*)(src), \
    (__attribute__((address_space(3))) void*)(dst), 16, 0, 0)

#define STAGE_A(h, bufo, koff) do { \
    GLL16(Ab + (size_t)((h)*128 + 0) * lda + (koff), sAll + (bufo) + (h)*16384 + 0*8192 + tid*16); \
    GLL16(Ab + (size_t)((h)*128 + 64) * lda + (koff), sAll + (bufo) + (h)*16384 + 1*8192 + tid*16); \
  } while (0)
#define STAGE_B(h, bufo, koff) do { \
    GLL16(Bb + (size_t)((h)*128 + 0) * ldb + (koff), sAll + (bufo) + 32768 + (h)*16384 + 0*8192 + tid*16); \
    GLL16(Bb + (size_t)((h)*128 + 64) * ldb + (koff), sAll + (bufo) + 32768 + (h)*16384 + 1*8192 + tid*16); \
  } while (0)

template<int MODE>
__global__ __launch_bounds__(512, 2) void gemm256_kernel(
    const __hip_bfloat16* __restrict__ A, int lda, long strideA,
    const __hip_bfloat16* __restrict__ Bt, int ldb, long strideB,
    float* __restrict__ Cf, __hip_bfloat16* __restrict__ Cb, int ldc, long strideC,
    const float* __restrict__ bias, long strideBias,
    const float* __restrict__ res,
    int K)
{
  __shared__ __align__(16) char sAll[2 * 65536];   // 128 KB: 2 x (A 32KB + B 32KB)

  const int z = blockIdx.z;
  A    += (size_t)z * strideA;
  Bt   += (size_t)z * strideB;
  bias += (size_t)z * strideBias;
  const long cOff = (long)z * strideC;

  const long tileM = (long)blockIdx.x * 256;   // M fastest -> resident blocks share B
  const int  tileN = blockIdx.y * 256;

  const int tid  = threadIdx.x;          // 0..511
  const int lane = tid & 63;
  const int wv   = tid >> 6;             // 0..7
  const int wm   = wv & 1;               // wave M half
  const int wn   = wv >> 1;              // wave N quarter (0..3)

  // staging source coords: thread t covers row (t>>3) (+ih*64 per issue), granule t&7;
  // source chunk = granule ^ (row&7)  (inverse of the read-side XOR)
  const int srow  = tid >> 3;                     // 0..63
  const int selem = ((tid & 7) ^ (srow & 7)) * 8; // pre-swizzled k-element offset

  const __hip_bfloat16* Ab = A  + (tileM + srow) * (size_t)lda + selem;
  const __hip_bfloat16* Bb = Bt + ((long)tileN + srow) * (size_t)ldb + selem;

  // fragment read coords
  const int fk   = lane >> 4;                     // k-slot 0..3
  const int fx   = lane & 7;
  const int arow = (wm*64 + (lane & 15)) * 128;   // byte row base in A-half
  const int brow = (wn*32 + (lane & 15)) * 128;   // byte row base in B-half
  const int ax0  = ((0*4 + fk) ^ fx) * 16;        // kk=0 swizzled chunk byte
  const int ax1  = ((1*4 + fk) ^ fx) * 16;        // kk=1

  f32x4 acc[2][2][4][2] = {};
  const int T = K / 64;

  // ---- prologue: stage tile 0 (order A0, B0, B1, A1 -> matches loop counts) ----
  STAGE_A(0, 0, 0);
  STAGE_B(0, 0, 0);
  STAGE_B(1, 0, 0);
  STAGE_A(1, 0, 0);

  for (int t = 0; t < T; ++t) {
    const int buf  = (t & 1) * 65536;
    const int nbuf = 65536 - buf;
    const int kn   = ((t + 1 < T) ? (t + 1) : t) * 64;  // clamped: last iter re-stages (unused)

    short8 aF[4][2], bF0[2][2], bF1[2][2];

    // ---------------- P1: quadrant (0,0) ----------------
    asm volatile("s_waitcnt vmcnt(4)" ::: "memory");   // A0(t),B0(t) landed
    __builtin_amdgcn_s_barrier();
    STAGE_A(0, nbuf, kn);
    {
      const char* sA = sAll + buf;                     // A-half0
      const char* sB = sAll + buf + 32768;             // B-half0
      #pragma unroll
      for (int i = 0; i < 4; ++i) {
        aF[i][0] = *(const short8*)(sA + arow + i*2048 + ax0);
        aF[i][1] = *(const short8*)(sA + arow + i*2048 + ax1);
      }
      #pragma unroll
      for (int j = 0; j < 2; ++j) {
        bF0[j][0] = *(const short8*)(sB + brow + j*2048 + ax0);
        bF0[j][1] = *(const short8*)(sB + brow + j*2048 + ax1);
      }
    }
    __builtin_amdgcn_s_setprio(1);
    #pragma unroll
    for (int i = 0; i < 4; ++i)
      #pragma unroll
      for (int j = 0; j < 2; ++j) {
        acc[0][0][i][j] = __builtin_amdgcn_mfma_f32_16x16x32_bf16(aF[i][0], bF0[j][0], acc[0][0][i][j], 0, 0, 0);
        acc[0][0][i][j] = __builtin_amdgcn_mfma_f32_16x16x32_bf16(aF[i][1], bF0[j][1], acc[0][0][i][j], 0, 0, 0);
      }
    __builtin_amdgcn_s_setprio(0);

    // ---------------- P2: quadrant (0,1) ----------------
    STAGE_B(0, nbuf, kn);
    asm volatile("s_waitcnt vmcnt(6)" ::: "memory");   // B1(t) landed
    __builtin_amdgcn_s_barrier();
    {
      const char* sB = sAll + buf + 32768 + 16384;     // B-half1
      #pragma unroll
      for (int j = 0; j < 2; ++j) {
        bF1[j][0] = *(const short8*)(sB + brow + j*2048 + ax0);
        bF1[j][1] = *(const short8*)(sB + brow + j*2048 + ax1);
      }
    }
    __builtin_amdgcn_s_setprio(1);
    #pragma unroll
    for (int i = 0; i < 4; ++i)
      #pragma unroll
      for (int j = 0; j < 2; ++j) {
        acc[0][1][i][j] = __builtin_amdgcn_mfma_f32_16x16x32_bf16(aF[i][0], bF1[j][0], acc[0][1][i][j], 0, 0, 0);
        acc[0][1][i][j] = __builtin_amdgcn_mfma_f32_16x16x32_bf16(aF[i][1], bF1[j][1], acc[0][1][i][j], 0, 0, 0);
      }
    __builtin_amdgcn_s_setprio(0);

    // ---------------- P3: quadrant (1,1) ----------------
    STAGE_B(1, nbuf, kn);
    asm volatile("s_waitcnt vmcnt(6)" ::: "memory");   // A1(t) landed
    __builtin_amdgcn_s_barrier();
    {
      const char* sA = sAll + buf + 16384;             // A-half1
      #pragma unroll
      for (int i = 0; i < 4; ++i) {
        aF[i][0] = *(const short8*)(sA + arow + i*2048 + ax0);
        aF[i][1] = *(const short8*)(sA + arow + i*2048 + ax1);
      }
    }
    __builtin_amdgcn_s_setprio(1);
    #pragma unroll
    for (int i = 0; i < 4; ++i)
      #pragma unroll
      for (int j = 0; j < 2; ++j) {
        acc[1][1][i][j] = __builtin_amdgcn_mfma_f32_16x16x32_bf16(aF[i][0], bF1[j][0], acc[1][1][i][j], 0, 0, 0);
        acc[1][1][i][j] = __builtin_amdgcn_mfma_f32_16x16x32_bf16(aF[i][1], bF1[j][1], acc[1][1][i][j], 0, 0, 0);
      }
    __builtin_amdgcn_s_setprio(0);

    // ---------------- P4: quadrant (1,0), registers only ----------------
    STAGE_A(1, nbuf, kn);
    __builtin_amdgcn_s_setprio(1);
    #pragma unroll
    for (int i = 0; i < 4; ++i)
      #pragma unroll
      for (int j = 0; j < 2; ++j) {
        acc[1][0][i][j] = __builtin_amdgcn_mfma_f32_16x16x32_bf16(aF[i][0], bF0[j][0], acc[1][0][i][j], 0, 0, 0);
        acc[1][0][i][j] = __builtin_amdgcn_mfma_f32_16x16x32_bf16(aF[i][1], bF0[j][1], acc[1][0][i][j], 0, 0, 0);
      }
    __builtin_amdgcn_s_setprio(0);
  }

  asm volatile("s_waitcnt vmcnt(0)" ::: "memory");     // drain tail stages before exit

  // epilogue: C/D layout col=lane&15, row=(lane>>4)*4+reg
  #pragma unroll
  for (int ih = 0; ih < 2; ++ih)
    #pragma unroll
    for (int jh = 0; jh < 2; ++jh)
      #pragma unroll
      for (int i = 0; i < 4; ++i) {
        const long row0 = tileM + ih*128 + wm*64 + i*16 + ((lane >> 4) * 4);
        #pragma unroll
        for (int j = 0; j < 2; ++j) {
          const int col = tileN + jh*128 + wn*32 + j*16 + (lane & 15);
          const float bv = bias[col];
          #pragma unroll
          for (int r = 0; r < 4; ++r) {
            const long idx = cOff + (row0 + r) * (long)ldc + col;
            const float v = acc[ih][jh][i][j][r] + bv;
            if (MODE == 0) {
              Cb[idx] = f2bf(v);
            } else if (MODE == 1 || MODE == 3) {
              Cf[idx] = v + res[idx];
            } else {
              Cb[idx] = f2bf(gelu_f(v));
            }
          }
        }
      }
}

extern "C" void kernel_launch(void* const* d_in, const int* in_sizes, int n_in,
                              void* d_out, int out_size, void* d_ws, size_t ws_size,
                              hipStream_t stream)
{
  const float* x     = (const float*)d_in[0];
  const float* W_qkv = (const float*)d_in[1];
  const float* b_qkv = (const float*)d_in[2];
  const float* W_out = (const float*)d_in[3];
  const float* b_out = (const float*)d_in[4];
  const float* ln1_g = (const float*)d_in[5];
  const float* ln1_b = (const float*)d_in[6];
  const float* ln2_g = (const float*)d_in[7];
  const float* ln2_b = (const float*)d_in[8];
  const float* W1    = (const float*)d_in[9];
  const float* b1    = (const float*)d_in[10];
  const float* W2    = (const float*)d_in[11];
  const float* b2    = (const float*)d_in[12];
  float* out = (float*)d_out;   // holds xr after fc_out, final result after MLP2

  // workspace layout (bytes); region [0,192MB) is overlaid phase-by-phase
  char* ws = (char*)d_ws;
  __hip_bfloat16* h     = (__hip_bfloat16*)(ws + 0);           // 48 MB   (LN1 -> QKV)
  __hip_bfloat16* qkv   = (__hip_bfloat16*)(ws + 50331648);    // 144 MB  (QKV -> attn)
  __hip_bfloat16* ctx   = (__hip_bfloat16*)(ws + 0);           // 48 MB   (attn -> fc_out), reuses h
  __hip_bfloat16* act   = (__hip_bfloat16*)(ws + 0);           // 192 MB  (MLP1 -> MLP2), reuses h+qkv
  __hip_bfloat16* yln   = (__hip_bfloat16*)(ws + 201326592);   // 48 MB   (LN2 -> MLP1)
  __hip_bfloat16* wqkvT = (__hip_bfloat16*)(ws + 251658240);   // 1.18 MB
  __hip_bfloat16* woutT = (__hip_bfloat16*)(ws + 252837888);   // 128 KB
  __hip_bfloat16* w1T   = (__hip_bfloat16*)(ws + 252968960);   // 4.5 MB
  __hip_bfloat16* w2T   = (__hip_bfloat16*)(ws + 257687552);   // 4.5 MB

  // weight prep: fp32 [K,N] -> bf16 [N,K], LDS-tiled
  transpose_bf16_kernel<<<dim3(768/32, 256/32, 3), 256, 0, stream>>>(W_qkv, wqkvT, 256, 768);
  transpose_bf16_kernel<<<dim3(256/32, 256/32, 1), 256, 0, stream>>>(W_out, woutT, 256, 256);
  transpose_bf16_kernel<<<dim3(3072/32, 768/32, 1), 256, 0, stream>>>(W1, w1T, 768, 3072);
  transpose_bf16_kernel<<<dim3(768/32, 3072/32, 1), 256, 0, stream>>>(W2, w2T, 3072, 768);

  // LN1: x -> h (bf16)
  ln_kernel<<<32768, 256, 0, stream>>>(x, ln1_g, ln1_b, h);

  // QKV: per channel c: h[:, c*256:(c+1)*256] @ W_qkv[c] + b_qkv[c] -> qkv[:, c, :]
  gemm256_kernel<0><<<dim3(32768/256, 768/256, 3), 512, 0, stream>>>(
      h, 768, 256, wqkvT, 256, 768*256, nullptr, qkv, 2304, 768, b_qkv, 768, nullptr, 256);

  // per-(row,kf) 3x3 softmax attention -> ctx
  attn_kernel<<<16384, 256, 0, stream>>>((const __hip_bfloat162*)qkv, (__hip_bfloat162*)ctx);

  // fc_out: ctx[98304,256] @ W_out + b_out + x -> xr (fp32, into d_out)
  gemm_bt_kernel<1><<<dim3(98304/BM, 256/BN, 1), 256, 0, stream>>>(
      ctx, 256, 0, woutT, 256, 0, out, nullptr, 256, 0, b_out, 0, x, 256);

  // LN2: xr -> yln (bf16)
  ln_kernel<<<32768, 256, 0, stream>>>(out, ln2_g, ln2_b, yln);

  // MLP1: yln @ W1 + b1, GELU -> act (bf16)
  gemm256_kernel<2><<<dim3(32768/256, 3072/256, 1), 512, 0, stream>>>(
      yln, 768, 0, w1T, 768, 0, nullptr, act, 3072, 0, b1, 0, nullptr, 768);

  // MLP2: act @ W2 + b2 + xr -> out (fp32, in-place residual read)
  gemm256_kernel<3><<<dim3(32768/256, 768/256, 1), 512, 0, stream>>>(
      act, 3072, 0, w2T, 3072, 0, out, nullptr, 768, 0, b2, 0, out, 3072);
}

// Round 3
// 770.588 us; speedup vs baseline: 1.1594x; 1.0216x over previous
//
#include <hip/hip_runtime.h>
#include <hip/hip_bf16.h>
#include <math.h>

typedef __attribute__((ext_vector_type(8))) short short8;
typedef __attribute__((ext_vector_type(4))) float f32x4;

__device__ __forceinline__ float bf2f(__hip_bfloat16 h) { return __bfloat162float(h); }
__device__ __forceinline__ __hip_bfloat16 f2bf(float f) { return __float2bfloat16(f); }

// tanh-approx GELU (max dev from exact ~3e-4; threshold is 0.15)
__device__ __forceinline__ float gelu_f(float v) {
  const float u = v * (0.7978845608f + 0.0356774081f * v * v);
  const float e = __expf(2.0f * u);                                // e^{2u}
  const float t = 1.0f - 2.0f * __builtin_amdgcn_rcpf(e + 1.0f);   // tanh(u)
  return 0.5f * v * (1.0f + t);
}

// ---------------- LayerNorm over 768, fp32 in -> bf16 out ----------------
__global__ __launch_bounds__(256) void ln_kernel(
    const float* __restrict__ in, const float* __restrict__ g,
    const float* __restrict__ b, __hip_bfloat16* __restrict__ out)
{
  __shared__ float sm1[4], sm2[4];
  const int row = blockIdx.x;
  const int tid = threadIdx.x;
  const float* p = in + (size_t)row * 768;
  float x0 = p[tid], x1 = p[tid + 256], x2 = p[tid + 512];
  float s = x0 + x1 + x2;
  #pragma unroll
  for (int off = 32; off > 0; off >>= 1) s += __shfl_down(s, off, 64);
  const int l = tid & 63, w = tid >> 6;
  if (l == 0) sm1[w] = s;
  __syncthreads();
  const float mu = (sm1[0] + sm1[1] + sm1[2] + sm1[3]) * (1.0f / 768.0f);
  const float d0 = x0 - mu, d1 = x1 - mu, d2 = x2 - mu;
  float ss = d0*d0 + d1*d1 + d2*d2;
  #pragma unroll
  for (int off = 32; off > 0; off >>= 1) ss += __shfl_down(ss, off, 64);
  if (l == 0) sm2[w] = ss;
  __syncthreads();
  const float var = (sm2[0] + sm2[1] + sm2[2] + sm2[3]) * (1.0f / 768.0f);
  const float rstd = rsqrtf(var + 1e-6f);
  __hip_bfloat16* q = out + (size_t)row * 768;
  q[tid]       = f2bf(d0 * rstd * g[tid]       + b[tid]);
  q[tid + 256] = f2bf(d1 * rstd * g[tid + 256] + b[tid + 256]);
  q[tid + 512] = f2bf(d2 * rstd * g[tid + 512] + b[tid + 512]);
}

// ---------------- criss-cross attention core, 2 kf per thread ----------------
__global__ __launch_bounds__(256) void attn_kernel(
    const __hip_bfloat162* __restrict__ qkv, __hip_bfloat162* __restrict__ ctx)
{
  const long t = (long)blockIdx.x * 256 + threadIdx.x;  // one per (row, kf-pair)
  const long row = t >> 7;
  const int kp = (int)(t & 127);                        // pair index 0..127
  const __hip_bfloat162* p = qkv + row * 1152;          // 2304 bf16 = 1152 pairs
  float q[3][2], k[3][2], v[3][2];
  #pragma unroll
  for (int c = 0; c < 3; ++c) {
    __hip_bfloat162 qq = p[c*384 + kp];
    __hip_bfloat162 kk = p[c*384 + 128 + kp];
    __hip_bfloat162 vv = p[c*384 + 256 + kp];
    q[c][0] = __low2float(qq); q[c][1] = __high2float(qq);
    k[c][0] = __low2float(kk); k[c][1] = __high2float(kk);
    v[c][0] = __low2float(vv); v[c][1] = __high2float(vv);
  }
  float o[3][2] = {};
  #pragma unroll
  for (int u = 0; u < 2; ++u) {
    #pragma unroll
    for (int c = 0; c < 3; ++c) {
      const float s0 = q[c][u]*k[0][u]*0.0625f, s1 = q[c][u]*k[1][u]*0.0625f, s2 = q[c][u]*k[2][u]*0.0625f;
      const float m = fmaxf(s0, fmaxf(s1, s2));
      const float e0 = __expf(s0-m), e1 = __expf(s1-m), e2 = __expf(s2-m);
      const float inv = v[c][u] / (e0 + e1 + e2);
      o[0][u] += e0*inv; o[1][u] += e1*inv; o[2][u] += e2*inv;
    }
  }
  __hip_bfloat162* po = ctx + row * 384;
  #pragma unroll
  for (int d = 0; d < 3; ++d)
    po[d*128 + kp] = __hip_bfloat162{f2bf(o[d][0]), f2bf(o[d][1])};
}

// ---------------- LDS-tiled fp32 [K,N] -> bf16 [N,K] transpose ----------------
__global__ __launch_bounds__(256) void transpose_bf16_kernel(
    const float* __restrict__ in, __hip_bfloat16* __restrict__ out, int K, int N)
{
  __shared__ float tile[32][33];
  in  += (size_t)blockIdx.z * K * N;
  out += (size_t)blockIdx.z * K * N;
  const int n0 = blockIdx.x * 32;
  const int k0 = blockIdx.y * 32;
  const int tx = threadIdx.x & 31, ty = threadIdx.x >> 5;   // 32 x 8
  #pragma unroll
  for (int r = 0; r < 32; r += 8)
    tile[ty + r][tx] = in[(size_t)(k0 + ty + r) * N + n0 + tx];
  __syncthreads();
  #pragma unroll
  for (int r = 0; r < 32; r += 8)
    out[(size_t)(n0 + ty + r) * K + k0 + tx] = f2bf(tile[tx][ty + r]);
}

// ---------------- bf16 MFMA GEMM, B^T input, BK=32, dbuf-pipelined ----------------
// (kept for fc_out, which is memory-bound at N=256/K=256)
#define BM 128
#define BN 128
#define BK 32

template<int MODE>
__global__ __launch_bounds__(256) void gemm_bt_kernel(
    const __hip_bfloat16* __restrict__ A, int lda, long strideA,
    const __hip_bfloat16* __restrict__ Bt, int ldb, long strideB,
    float* __restrict__ Cf, __hip_bfloat16* __restrict__ Cb, int ldc, long strideC,
    const float* __restrict__ bias, long strideBias,
    const float* __restrict__ res,
    int K)
{
  __shared__ __align__(16) char sAll[2 * 16384];   // 2 x (sA 8KB + sB 8KB)

  const int z = blockIdx.z;
  A    += (size_t)z * strideA;
  Bt   += (size_t)z * strideB;
  bias += (size_t)z * strideBias;
  const long cOff = (long)z * strideC;

  const long tileM = (long)blockIdx.x * BM;   // M fastest
  const int  tileN = blockIdx.y * BN;

  const int tid  = threadIdx.x;
  const int lane = tid & 63;
  const int wv   = tid >> 6;
  const int waveM = (wv & 1) * 64;
  const int waveN = (wv >> 1) * 64;

  const int srow  = tid >> 2;                          // 0..63
  const int selem = ((tid & 3) ^ ((srow >> 1) & 3)) * 8;
  const int frow = lane & 15;
  const int fkb  = (((lane >> 4) ^ ((frow >> 1) & 3)) << 4);  // swizzled byte offs

  const __hip_bfloat16* Ab = A  + tileM * (size_t)lda + selem;
  const __hip_bfloat16* Bb = Bt + (long)tileN * (size_t)ldb + selem;

  f32x4 acc[4][4] = {};

  const int T = K / BK;

  {
    #pragma unroll
    for (int hh = 0; hh < 2; ++hh) {
      const int r = hh * 64 + srow;
      __builtin_amdgcn_global_load_lds(
          (const __attribute__((address_space(1))) void*)(Ab + (size_t)r * lda),
          (__attribute__((address_space(3))) void*)(sAll + hh*4096 + tid*16), 16, 0, 0);
      __builtin_amdgcn_global_load_lds(
          (const __attribute__((address_space(1))) void*)(Bb + (size_t)r * ldb),
          (__attribute__((address_space(3))) void*)(sAll + 8192 + hh*4096 + tid*16), 16, 0, 0);
    }
  }

  for (int t = 0; t < T; ++t) {
    const int buf = (t & 1) * 16384;
    if (t + 1 < T) {
      const int nbuf = 16384 - buf;
      const int k0 = (t + 1) * BK;
      #pragma unroll
      for (int hh = 0; hh < 2; ++hh) {
        const int r = hh * 64 + srow;
        __builtin_amdgcn_global_load_lds(
            (const __attribute__((address_space(1))) void*)(Ab + (size_t)r * lda + k0),
            (__attribute__((address_space(3))) void*)(sAll + nbuf + hh*4096 + tid*16), 16, 0, 0);
        __builtin_amdgcn_global_load_lds(
            (const __attribute__((address_space(1))) void*)(Bb + (size_t)r * ldb + k0),
            (__attribute__((address_space(3))) void*)(sAll + nbuf + 8192 + hh*4096 + tid*16), 16, 0, 0);
      }
      asm volatile("s_waitcnt vmcnt(4)" ::: "memory");   // drain tile t only
    } else {
      asm volatile("s_waitcnt vmcnt(0)" ::: "memory");
    }
    __builtin_amdgcn_s_barrier();                        // buf[t] published
    asm volatile("" ::: "memory");

    const char* sAb = sAll + buf;
    const char* sBb = sAb + 8192;
    short8 aF[4], bF[4];
    #pragma unroll
    for (int i = 0; i < 4; ++i)
      aF[i] = *(const short8*)(sAb + (waveM + i*16 + frow) * 64 + fkb);
    #pragma unroll
    for (int j = 0; j < 4; ++j)
      bF[j] = *(const short8*)(sBb + (waveN + j*16 + frow) * 64 + fkb);
    #pragma unroll
    for (int i = 0; i < 4; ++i)
      #pragma unroll
      for (int j = 0; j < 4; ++j)
        acc[i][j] = __builtin_amdgcn_mfma_f32_16x16x32_bf16(aF[i], bF[j], acc[i][j], 0, 0, 0);

    __builtin_amdgcn_s_barrier();                        // readers of buf[t] done
  }

  #pragma unroll
  for (int i = 0; i < 4; ++i) {
    const long row0 = tileM + waveM + i*16 + ((lane >> 4) * 4);
    #pragma unroll
    for (int j = 0; j < 4; ++j) {
      const int col = tileN + waveN + j*16 + (lane & 15);
      const float bv = bias[col];
      #pragma unroll
      for (int r = 0; r < 4; ++r) {
        const long idx = cOff + (row0 + r) * (long)ldc + col;
        const float v = acc[i][j][r] + bv;
        if (MODE == 0) {
          Cb[idx] = f2bf(v);
        } else if (MODE == 1 || MODE == 3) {
          Cf[idx] = v + res[idx];
        } else {
          Cb[idx] = f2bf(gelu_f(v));
        }
      }
    }
  }
}

// ---------------- 256x256 8-wave 4-phase bf16 GEMM (BK=64, counted-vmcnt) ----------------
// LDS: 2 parity buffers x 64KB; slots A-half h at h*16384, B-half h at 32768+h*16384.
// Per K-tile t (parity p=t&1, q=p^1), phases = quadrants (0,0),(0,1),(1,1),(1,0).
// Stage order per tile t: P1 A1(t+1)->q, P2 B0(t+1)->q, P3 A0(t+2)->p, P4 B1(t+2)->p.
// FIFO ledger: the newest half-tile of tile t is B0(t), issued at P2 of t-1; after it
// exactly 2 stages (A0(t+1), B1(t+1)) = 4 loads are issued before P1 of t. Hence
//   P1: s_waitcnt vmcnt(4); s_barrier  ==> ALL of tile t landed (every wave's stages),
// while 2 half-tiles stay in flight. ds_reads come strictly AFTER this barrier.
// Slot-overwrite safety (write lands only after issue; issue ordered by barriers):
//   A1(q)@P1, B0(q)@P2: their previous readers drained before each wave reached the
//     P1-start barrier of tile t (lgkmcnt(0) precedes every MFMA).           [P1 bar]
//   A0(p)@P3: readers are P1 of t, drained before end-P1 barrier.            [end-P1]
//   B1(p)@P4: readers are P2 of t, drained before end-P2 barrier.            [end-P2]
// vmcnt never drains to 0 inside the loop.
#define GLL16(src, dst) __builtin_amdgcn_global_load_lds( \
    (const __attribute__((address_space(1))) void*)(src), \
    (__attribute__((address_space(3))) void*)(dst), 16, 0, 0)

#define STAGE_AH(h, pb, koff) do { \
    GLL16(Ab + (size_t)((h)*128 + 0 ) * lda + (koff), sAll + (pb)*65536 + (h)*16384 + 0    + tid*16); \
    GLL16(Ab + (size_t)((h)*128 + 64) * lda + (koff), sAll + (pb)*65536 + (h)*16384 + 8192 + tid*16); \
  } while (0)
#define STAGE_BH(h, pb, koff) do { \
    GLL16(Bb + (size_t)((h)*128 + 0 ) * ldb + (koff), sAll + (pb)*65536 + 32768 + (h)*16384 + 0    + tid*16); \
    GLL16(Bb + (size_t)((h)*128 + 64) * ldb + (koff), sAll + (pb)*65536 + 32768 + (h)*16384 + 8192 + tid*16); \
  } while (0)

template<int MODE>
__global__ __launch_bounds__(512, 2) void gemm256_kernel(
    const __hip_bfloat16* __restrict__ A, int lda, long strideA,
    const __hip_bfloat16* __restrict__ Bt, int ldb, long strideB,
    float* __restrict__ Cf, __hip_bfloat16* __restrict__ Cb, int ldc, long strideC,
    const float* __restrict__ bias, long strideBias,
    const float* __restrict__ res,
    int K)
{
  __shared__ __align__(16) char sAll[2 * 65536];   // 128 KB

  const int z = blockIdx.z;
  A    += (size_t)z * strideA;
  Bt   += (size_t)z * strideB;
  bias += (size_t)z * strideBias;
  const long cOff = (long)z * strideC;

  const long tileM = (long)blockIdx.x * 256;   // M fastest -> resident blocks share B
  const int  tileN = blockIdx.y * 256;

  const int tid  = threadIdx.x;          // 0..511
  const int lane = tid & 63;
  const int wv   = tid >> 6;             // 0..7
  const int wm   = wv & 1;               // wave M half
  const int wn   = wv >> 1;              // wave N quarter (0..3)

  // staging: thread t covers row (tid>>3) (+64 per second GLL), granule tid&7;
  // source chunk = granule ^ (row&7)  (inverse of the read-side XOR)
  const int srow  = tid >> 3;                     // 0..63
  const int selem = ((tid & 7) ^ (srow & 7)) * 8; // pre-swizzled k-element offset

  const __hip_bfloat16* Ab = A  + (tileM + srow) * (size_t)lda + selem;
  const __hip_bfloat16* Bb = Bt + ((long)tileN + srow) * (size_t)ldb + selem;

  // fragment read coords (row stride 128 B; granule = chunk ^ (row&7))
  const int fk   = lane >> 4;                     // k-slot 0..3
  const int fx   = lane & 7;
  const int arow = (wm*64 + (lane & 15)) * 128;   // byte row base in A-half slot
  const int brow = (wn*32 + (lane & 15)) * 128;   // byte row base in B-half slot
  const int ax0  = ((0*4 + fk) ^ fx) * 16;        // kk=0 swizzled chunk byte
  const int ax1  = ((1*4 + fk) ^ fx) * 16;        // kk=1

  f32x4 acc[2][2][4][2] = {};
  const int T = K / 64;

  // ---- prologue: tile 0 (parity 0) complete, then A0(1), B1(1) (parity 1) ----
  STAGE_AH(0, 0, 0);
  STAGE_BH(0, 0, 0);
  STAGE_BH(1, 0, 0);
  STAGE_AH(1, 0, 0);
  {
    const int k1 = (T > 1 ? 1 : 0) * 64;
    STAGE_AH(0, 1, k1);
    STAGE_BH(1, 1, k1);
  }

  for (int t = 0; t < T; ++t) {
    const int p = t & 1;
    const int q = p ^ 1;
    const int kn1 = (t + 1 < T ? t + 1 : T - 1) * 64;   // tile t+1 stages (parity q)
    const int kn2 = (t + 2 < T ? t + 2 : T - 1) * 64;   // tile t+2 stages (parity p)
    const char* sA = sAll + p * 65536;
    const char* sB = sA + 32768;

    short8 aF[4][2], bF0[2][2], bF1[2][2];

    // ---------------- P1: quadrant (0,0) ----------------
    asm volatile("s_waitcnt vmcnt(4)" ::: "memory");     // all of tile t landed (per wave)
    __builtin_amdgcn_s_barrier();                        // ... for every wave
    asm volatile("" ::: "memory");                       // pin reads below barrier
    #pragma unroll
    for (int i = 0; i < 4; ++i) {
      aF[i][0] = *(const short8*)(sA + arow + i*2048 + ax0);
      aF[i][1] = *(const short8*)(sA + arow + i*2048 + ax1);
    }
    #pragma unroll
    for (int j = 0; j < 2; ++j) {
      bF0[j][0] = *(const short8*)(sB + brow + j*2048 + ax0);
      bF0[j][1] = *(const short8*)(sB + brow + j*2048 + ax1);
    }
    STAGE_AH(1, q, kn1);
    asm volatile("s_waitcnt lgkmcnt(0)" ::: "memory");
    __builtin_amdgcn_sched_barrier(0);
    __builtin_amdgcn_s_setprio(1);
    #pragma unroll
    for (int i = 0; i < 4; ++i)
      #pragma unroll
      for (int j = 0; j < 2; ++j) {
        acc[0][0][i][j] = __builtin_amdgcn_mfma_f32_16x16x32_bf16(aF[i][0], bF0[j][0], acc[0][0][i][j], 0, 0, 0);
        acc[0][0][i][j] = __builtin_amdgcn_mfma_f32_16x16x32_bf16(aF[i][1], bF0[j][1], acc[0][0][i][j], 0, 0, 0);
      }
    __builtin_amdgcn_s_setprio(0);
    __builtin_amdgcn_s_barrier();                        // end-P1: A0(p) readers drained

    // ---------------- P2: quadrant (0,1) ----------------
    #pragma unroll
    for (int j = 0; j < 2; ++j) {
      bF1[j][0] = *(const short8*)(sB + 16384 + brow + j*2048 + ax0);
      bF1[j][1] = *(const short8*)(sB + 16384 + brow + j*2048 + ax1);
    }
    STAGE_BH(0, q, kn1);
    asm volatile("s_waitcnt lgkmcnt(0)" ::: "memory");
    __builtin_amdgcn_sched_barrier(0);
    __builtin_amdgcn_s_setprio(1);
    #pragma unroll
    for (int i = 0; i < 4; ++i)
      #pragma unroll
      for (int j = 0; j < 2; ++j) {
        acc[0][1][i][j] = __builtin_amdgcn_mfma_f32_16x16x32_bf16(aF[i][0], bF1[j][0], acc[0][1][i][j], 0, 0, 0);
        acc[0][1][i][j] = __builtin_amdgcn_mfma_f32_16x16x32_bf16(aF[i][1], bF1[j][1], acc[0][1][i][j], 0, 0, 0);
      }
    __builtin_amdgcn_s_setprio(0);
    __builtin_amdgcn_s_barrier();                        // end-P2: B1(p) readers drained

    // ---------------- P3: quadrant (1,1) ----------------
    #pragma unroll
    for (int i = 0; i < 4; ++i) {
      aF[i][0] = *(const short8*)(sA + 16384 + arow + i*2048 + ax0);
      aF[i][1] = *(const short8*)(sA + 16384 + arow + i*2048 + ax1);
    }
    STAGE_AH(0, p, kn2);                                 // safe: end-P1 passed
    asm volatile("s_waitcnt lgkmcnt(0)" ::: "memory");
    __builtin_amdgcn_sched_barrier(0);
    __builtin_amdgcn_s_setprio(1);
    #pragma unroll
    for (int i = 0; i < 4; ++i)
      #pragma unroll
      for (int j = 0; j < 2; ++j) {
        acc[1][1][i][j] = __builtin_amdgcn_mfma_f32_16x16x32_bf16(aF[i][0], bF1[j][0], acc[1][1][i][j], 0, 0, 0);
        acc[1][1][i][j] = __builtin_amdgcn_mfma_f32_16x16x32_bf16(aF[i][1], bF1[j][1], acc[1][1][i][j], 0, 0, 0);
      }
    __builtin_amdgcn_s_setprio(0);

    // ---------------- P4: quadrant (1,0), registers only ----------------
    STAGE_BH(1, p, kn2);                                 // safe: end-P2 passed
    __builtin_amdgcn_s_setprio(1);
    #pragma unroll
    for (int i = 0; i < 4; ++i)
      #pragma unroll
      for (int j = 0; j < 2; ++j) {
        acc[1][0][i][j] = __builtin_amdgcn_mfma_f32_16x16x32_bf16(aF[i][0], bF0[j][0], acc[1][0][i][j], 0, 0, 0);
        acc[1][0][i][j] = __builtin_amdgcn_mfma_f32_16x16x32_bf16(aF[i][1], bF0[j][1], acc[1][0][i][j], 0, 0, 0);
      }
    __builtin_amdgcn_s_setprio(0);
  }

  asm volatile("s_waitcnt vmcnt(0)" ::: "memory");       // drain tail stages before exit

  // epilogue: C/D layout col=lane&15, row=(lane>>4)*4+reg
  #pragma unroll
  for (int ih = 0; ih < 2; ++ih)
    #pragma unroll
    for (int jh = 0; jh < 2; ++jh)
      #pragma unroll
      for (int i = 0; i < 4; ++i) {
        const long row0 = tileM + ih*128 + wm*64 + i*16 + ((lane >> 4) * 4);
        #pragma unroll
        for (int j = 0; j < 2; ++j) {
          const int col = tileN + jh*128 + wn*32 + j*16 + (lane & 15);
          const float bv = bias[col];
          #pragma unroll
          for (int r = 0; r < 4; ++r) {
            const long idx = cOff + (row0 + r) * (long)ldc + col;
            const float v = acc[ih][jh][i][j][r] + bv;
            if (MODE == 0) {
              Cb[idx] = f2bf(v);
            } else if (MODE == 1 || MODE == 3) {
              Cf[idx] = v + res[idx];
            } else {
              Cb[idx] = f2bf(gelu_f(v));
            }
          }
        }
      }
}

extern "C" void kernel_launch(void* const* d_in, const int* in_sizes, int n_in,
                              void* d_out, int out_size, void* d_ws, size_t ws_size,
                              hipStream_t stream)
{
  const float* x     = (const float*)d_in[0];
  const float* W_qkv = (const float*)d_in[1];
  const float* b_qkv = (const float*)d_in[2];
  const float* W_out = (const float*)d_in[3];
  const float* b_out = (const float*)d_in[4];
  const float* ln1_g = (const float*)d_in[5];
  const float* ln1_b = (const float*)d_in[6];
  const float* ln2_g = (const float*)d_in[7];
  const float* ln2_b = (const float*)d_in[8];
  const float* W1    = (const float*)d_in[9];
  const float* b1    = (const float*)d_in[10];
  const float* W2    = (const float*)d_in[11];
  const float* b2    = (const float*)d_in[12];
  float* out = (float*)d_out;   // holds xr after fc_out, final result after MLP2

  // workspace layout (bytes); region [0,192MB) is overlaid phase-by-phase
  char* ws = (char*)d_ws;
  __hip_bfloat16* h     = (__hip_bfloat16*)(ws + 0);           // 48 MB   (LN1 -> QKV)
  __hip_bfloat16* qkv   = (__hip_bfloat16*)(ws + 50331648);    // 144 MB  (QKV -> attn)
  __hip_bfloat16* ctx   = (__hip_bfloat16*)(ws + 0);           // 48 MB   (attn -> fc_out), reuses h
  __hip_bfloat16* act   = (__hip_bfloat16*)(ws + 0);           // 192 MB  (MLP1 -> MLP2), reuses h+qkv
  __hip_bfloat16* yln   = (__hip_bfloat16*)(ws + 201326592);   // 48 MB   (LN2 -> MLP1)
  __hip_bfloat16* wqkvT = (__hip_bfloat16*)(ws + 251658240);   // 1.18 MB
  __hip_bfloat16* woutT = (__hip_bfloat16*)(ws + 252837888);   // 128 KB
  __hip_bfloat16* w1T   = (__hip_bfloat16*)(ws + 252968960);   // 4.5 MB
  __hip_bfloat16* w2T   = (__hip_bfloat16*)(ws + 257687552);   // 4.5 MB

  // weight prep: fp32 [K,N] -> bf16 [N,K], LDS-tiled
  transpose_bf16_kernel<<<dim3(768/32, 256/32, 3), 256, 0, stream>>>(W_qkv, wqkvT, 256, 768);
  transpose_bf16_kernel<<<dim3(256/32, 256/32, 1), 256, 0, stream>>>(W_out, woutT, 256, 256);
  transpose_bf16_kernel<<<dim3(3072/32, 768/32, 1), 256, 0, stream>>>(W1, w1T, 768, 3072);
  transpose_bf16_kernel<<<dim3(768/32, 3072/32, 1), 256, 0, stream>>>(W2, w2T, 3072, 768);

  // LN1: x -> h (bf16)
  ln_kernel<<<32768, 256, 0, stream>>>(x, ln1_g, ln1_b, h);

  // QKV: per channel c: h[:, c*256:(c+1)*256] @ W_qkv[c] + b_qkv[c] -> qkv[:, c, :]
  gemm256_kernel<0><<<dim3(32768/256, 768/256, 3), 512, 0, stream>>>(
      h, 768, 256, wqkvT, 256, 768*256, nullptr, qkv, 2304, 768, b_qkv, 768, nullptr, 256);

  // per-(row,kf) 3x3 softmax attention -> ctx
  attn_kernel<<<16384, 256, 0, stream>>>((const __hip_bfloat162*)qkv, (__hip_bfloat162*)ctx);

  // fc_out: ctx[98304,256] @ W_out + b_out + x -> xr (fp32, into d_out)
  gemm_bt_kernel<1><<<dim3(98304/BM, 256/BN, 1), 256, 0, stream>>>(
      ctx, 256, 0, woutT, 256, 0, out, nullptr, 256, 0, b_out, 0, x, 256);

  // LN2: xr -> yln (bf16)
  ln_kernel<<<32768, 256, 0, stream>>>(out, ln2_g, ln2_b, yln);

  // MLP1: yln @ W1 + b1, GELU -> act (bf16)
  gemm256_kernel<2><<<dim3(32768/256, 3072/256, 1), 512, 0, stream>>>(
      yln, 768, 0, w1T, 768, 0, nullptr, act, 3072, 0, b1, 0, nullptr, 768);

  // MLP2: act @ W2 + b2 + xr -> out (fp32, in-place residual read)
  gemm256_kernel<3><<<dim3(32768/256, 768/256, 1), 512, 0, stream>>>(
      act, 3072, 0, w2T, 3072, 0, out, nullptr, 768, 0, b2, 0, out, 3072);
}